// Round 2
// baseline (458.999 us; speedup 1.0000x reference)
//
#include <hip/hip_runtime.h>

#define N_NODES 100000
#define N_EDGES 800000

typedef unsigned short u16;
typedef unsigned int u32;
typedef __attribute__((ext_vector_type(8))) short short8;
typedef __attribute__((ext_vector_type(4))) float floatx4;

__device__ __forceinline__ float bf2f(u16 u) {
    union { u32 i; float f; } v; v.i = ((u32)u) << 16; return v.f;
}
__device__ __forceinline__ u16 f2bf(float f) {
    union { float f; u32 i; } v; v.f = f;
    u32 r = (v.i + 0x7FFFu + ((v.i >> 16) & 1u)) >> 16;
    return (u16)r;
}

// ---------------- degree + CSR build ----------------

__global__ void k_zero(int* out_deg, int* in_deg) {
    int i = blockIdx.x * 256 + threadIdx.x;
    if (i < N_NODES) { out_deg[i] = 0; in_deg[i] = 0; }
}

__global__ void k_deg(const int* __restrict__ src, const int* __restrict__ dst,
                      int* out_deg, int* in_deg) {
    int e = blockIdx.x * 256 + threadIdx.x;
    if (e < N_EDGES) {
        atomicAdd(&out_deg[src[e]], 1);
        atomicAdd(&in_deg[dst[e]], 1);
    }
}

__global__ void k_scan1(const int* __restrict__ in_deg, int* blockSums) {
    __shared__ int red[256];
    int t = threadIdx.x;
    int base = blockIdx.x * 1024 + t * 4;
    int s = 0;
#pragma unroll
    for (int j = 0; j < 4; j++) { int idx = base + j; if (idx < N_NODES) s += in_deg[idx]; }
    red[t] = s; __syncthreads();
    for (int off = 128; off > 0; off >>= 1) {
        if (t < off) red[t] += red[t + off];
        __syncthreads();
    }
    if (t == 0) blockSums[blockIdx.x] = red[0];
}

__global__ void k_scan2(int* blockSums, int nb) {
    if (threadIdx.x == 0) {
        int acc = 0;
        for (int i = 0; i < nb; i++) { int v = blockSums[i]; blockSums[i] = acc; acc += v; }
    }
}

__global__ void k_scan3(const int* __restrict__ in_deg, const int* __restrict__ out_deg,
                        const int* __restrict__ blockSums,
                        int* csr_start, int* cursor, float* out_scale, float* in_scale) {
    __shared__ int sc[256];
    int t = threadIdx.x;
    int base = blockIdx.x * 1024 + t * 4;
    int d[4]; int s = 0;
#pragma unroll
    for (int j = 0; j < 4; j++) { int idx = base + j; d[j] = (idx < N_NODES) ? in_deg[idx] : 0; s += d[j]; }
    sc[t] = s; __syncthreads();
    for (int off = 1; off < 256; off <<= 1) {
        int v = (t >= off) ? sc[t - off] : 0;
        __syncthreads();
        sc[t] += v;
        __syncthreads();
    }
    int excl = sc[t] - s;
    int run = blockSums[blockIdx.x] + excl;
#pragma unroll
    for (int j = 0; j < 4; j++) {
        int idx = base + j;
        if (idx < N_NODES) {
            csr_start[idx] = run; cursor[idx] = run; run += d[j];
            int od = out_deg[idx]; if (od < 1) od = 1;
            out_scale[idx] = rsqrtf((float)od);
            int id = d[j]; if (id < 1) id = 1;
            in_scale[idx] = rsqrtf((float)id);
        }
    }
}

__global__ void k_scatter(const int* __restrict__ src, const int* __restrict__ dst,
                          const int* __restrict__ attr, int* cursor, int* csr_edge) {
    int e = blockIdx.x * 256 + threadIdx.x;
    if (e < N_EDGES) {
        int d = dst[e];
        int pos = atomicAdd(&cursor[d], 1);
        csr_edge[pos] = (src[e] << 5) | attr[e];
    }
}

// ---------------- fused node GEMMs: h_sum = feat_src@w1, h_prod = tanh(feat_src@w2 + bias) ----------------
// A-frag (16x16x32): A[m=lane&15][k=quad*8+j]; B[k][n=lane&15], k=quad*8+j; D: row=quad*4+reg, col=lane&15.

__global__ __launch_bounds__(256) void k_gemm(const float* __restrict__ feat,
                                              const float* __restrict__ w1, const float* __restrict__ w2,
                                              const float* __restrict__ out_scale,
                                              u16* __restrict__ h_sum, u16* __restrict__ h_prod) {
    __shared__ u16 ldsw[2 * 8 * 4 * 64 * 8];  // 64 KB, B-frag layout [mat][ot][ks][lane][j], bf16
    for (int idx = threadIdx.x; idx < 2 * 16384; idx += 256) {
        int m = idx >> 14; int r = idx & 16383;
        int k = r >> 7, o = r & 127;
        float val = m ? w2[k * 128 + o] : w1[k * 128 + o];
        int ot = o >> 4, ks = k >> 5, quad = (k >> 3) & 3, j = k & 7;
        int lane = (quad << 4) | (o & 15);
        ldsw[((((m * 8 + ot) * 4 + ks) * 64) + lane) * 8 + j] = f2bf(val);
    }
    __syncthreads();
    int wave = threadIdx.x >> 6, lane = threadIdx.x & 63;
    int quad = lane >> 4, l15 = lane & 15;
    const int NT = (N_NODES + 63) / 64;
    for (int tile = blockIdx.x; tile < NT; tile += gridDim.x) {
        int nb = tile * 64 + wave * 16;
        short8 a[4];
        int anode = nb + l15; if (anode >= N_NODES) anode = N_NODES - 1;
#pragma unroll
        for (int ks = 0; ks < 4; ks++) {
            const float* ap = feat + anode * 128 + ks * 32 + quad * 8;
            float4 f0 = *(const float4*)ap;
            float4 f1 = *(const float4*)(ap + 4);
            short8 av;
            av[0] = (short)f2bf(f0.x); av[1] = (short)f2bf(f0.y);
            av[2] = (short)f2bf(f0.z); av[3] = (short)f2bf(f0.w);
            av[4] = (short)f2bf(f1.x); av[5] = (short)f2bf(f1.y);
            av[6] = (short)f2bf(f1.z); av[7] = (short)f2bf(f1.w);
            a[ks] = av;
        }
        floatx4 acc[2][8];
#pragma unroll
        for (int m = 0; m < 2; m++)
#pragma unroll
            for (int ot = 0; ot < 8; ot++) acc[m][ot] = (floatx4){0.f, 0.f, 0.f, 0.f};
#pragma unroll
        for (int m = 0; m < 2; m++)
#pragma unroll
            for (int ot = 0; ot < 8; ot++)
#pragma unroll
                for (int ks = 0; ks < 4; ks++) {
                    short8 b = *(const short8*)&ldsw[((((m * 8 + ot) * 4 + ks) * 64) + lane) * 8];
                    acc[m][ot] = __builtin_amdgcn_mfma_f32_16x16x32_bf16(a[ks], b, acc[m][ot], 0, 0, 0);
                }
        float scl[4];
#pragma unroll
        for (int r = 0; r < 4; r++) {
            int node = nb + quad * 4 + r;
            scl[r] = (node < N_NODES) ? out_scale[node] : 1.0f;
        }
#pragma unroll
        for (int ot = 0; ot < 8; ot++) {
            int o = ot * 16 + l15;
            float bias = w2[128 * 128 + o];
#pragma unroll
            for (int r = 0; r < 4; r++) {
                int node = nb + quad * 4 + r;
                if (node < N_NODES) {
                    float hsv = acc[0][ot][r] * scl[r];
                    float hpv = tanhf(acc[1][ot][r] * scl[r] + bias);
                    h_sum[node * 128 + o] = f2bf(hsv);
                    h_prod[node * 128 + o] = f2bf(hpv);
                }
            }
        }
    }
}

// ---------------- edge stage: per-dst-node sum & product reduction over CSR ----------------
// writes hs (f32) directly into d_out; hp (bf16) to ws.

__global__ __launch_bounds__(256) void k_edge(const int* __restrict__ csr_start, const int* __restrict__ in_deg,
                                              const int* __restrict__ csr_edge,
                                              const u16* __restrict__ h_sum, const u16* __restrict__ h_prod,
                                              const float* __restrict__ bond_emb,
                                              float* __restrict__ out_hs, u16* __restrict__ hp) {
    __shared__ float ew[32 * 128];  // 16 KB, bond_emb as f32
    for (int i = threadIdx.x; i < 4096; i += 256) ew[i] = bond_emb[i];
    __syncthreads();
    int wave = threadIdx.x >> 6, lane = threadIdx.x & 63;
    int n = blockIdx.x * 4 + wave;
    if (n >= N_NODES) return;
    int start = csr_start[n], deg = in_deg[n];
    float s0 = 0.f, s1 = 0.f, p0 = 1.f, p1 = 1.f;
    const float* ewl = ew + 2 * lane;
    for (int i = 0; i < deg; i++) {
        int pk = csr_edge[start + i];
        int sn = pk >> 5, at = pk & 31;
        u32 up = *(const u32*)(h_prod + sn * 128 + 2 * lane);
        u32 us = *(const u32*)(h_sum + sn * 128 + 2 * lane);
        float e0 = ewl[at * 128], e1 = ewl[at * 128 + 1];
        float a0 = bf2f((u16)(up & 0xFFFF)), a1 = bf2f((u16)(up >> 16));
        float b0 = bf2f((u16)(us & 0xFFFF)), b1 = bf2f((u16)(us >> 16));
        p0 *= a0 * e0; p1 *= a1 * e1;
        s0 += b0 * e0; s1 += b1 * e1;
    }
    float2 sv; sv.x = s0; sv.y = s1;
    *(float2*)(out_hs + n * 128 + 2 * lane) = sv;
    u32 pp = ((u32)f2bf(p1) << 16) | (u32)f2bf(p0);
    *(u32*)(hp + n * 128 + 2 * lane) = pp;
}

// ---------------- final: out = (hs + hp@v) * in_scale ; hs lives in d_out ----------------

__global__ __launch_bounds__(256) void k_final(const u16* __restrict__ hp,
                                               const float* __restrict__ v, const float* __restrict__ in_scale,
                                               float* __restrict__ out) {
    __shared__ u16 ldsw[8 * 4 * 64 * 8];  // 32 KB
    for (int idx = threadIdx.x; idx < 16384; idx += 256) {
        int k = idx >> 7, o = idx & 127;
        int ot = o >> 4, ks = k >> 5, quad = (k >> 3) & 3, j = k & 7;
        int lane = (quad << 4) | (o & 15);
        ldsw[(((ot * 4 + ks) * 64) + lane) * 8 + j] = f2bf(v[k * 128 + o]);
    }
    __syncthreads();
    int wave = threadIdx.x >> 6, lane = threadIdx.x & 63;
    int quad = lane >> 4, l15 = lane & 15;
    const int NT = (N_NODES + 63) / 64;
    for (int tile = blockIdx.x; tile < NT; tile += gridDim.x) {
        int nb = tile * 64 + wave * 16;
        short8 a[4];
        int anode = nb + l15; if (anode >= N_NODES) anode = N_NODES - 1;
#pragma unroll
        for (int ks = 0; ks < 4; ks++)
            a[ks] = *(const short8*)(hp + anode * 128 + ks * 32 + quad * 8);
        floatx4 acc[8];
#pragma unroll
        for (int ot = 0; ot < 8; ot++) acc[ot] = (floatx4){0.f, 0.f, 0.f, 0.f};
#pragma unroll
        for (int ot = 0; ot < 8; ot++)
#pragma unroll
            for (int ks = 0; ks < 4; ks++) {
                short8 b = *(const short8*)&ldsw[(((ot * 4 + ks) * 64) + lane) * 8];
                acc[ot] = __builtin_amdgcn_mfma_f32_16x16x32_bf16(a[ks], b, acc[ot], 0, 0, 0);
            }
        float scl[4];
#pragma unroll
        for (int r = 0; r < 4; r++) {
            int node = nb + quad * 4 + r;
            scl[r] = (node < N_NODES) ? in_scale[node] : 0.f;
        }
#pragma unroll
        for (int ot = 0; ot < 8; ot++) {
            int o = ot * 16 + l15;
#pragma unroll
            for (int r = 0; r < 4; r++) {
                int node = nb + quad * 4 + r;
                if (node < N_NODES) {
                    float hsv = out[node * 128 + o];          // hs, written by k_edge
                    out[node * 128 + o] = (acc[ot][r] + hsv) * scl[r];
                }
            }
        }
    }
}

extern "C" void kernel_launch(void* const* d_in, const int* in_sizes, int n_in,
                              void* d_out, int out_size, void* d_ws, size_t ws_size,
                              hipStream_t stream) {
    const float* feat = (const float*)d_in[0];
    const int* src = (const int*)d_in[1];
    const int* dst = (const int*)d_in[2];
    const int* attr = (const int*)d_in[3];
    const float* w1 = (const float*)d_in[4];
    const float* w2 = (const float*)d_in[5];
    const float* v = (const float*)d_in[6];
    const float* bond = (const float*)d_in[7];
    float* out = (float*)d_out;

    char* ws = (char*)d_ws;
    size_t off = 0;
    auto alloc = [&](size_t bytes) -> char* {
        char* p = ws + off; off += (bytes + 255) & ~(size_t)255; return p;
    };
    int* out_deg   = (int*)alloc((size_t)N_NODES * 4);
    int* in_deg    = (int*)alloc((size_t)N_NODES * 4);
    int* csr_start = (int*)alloc((size_t)N_NODES * 4);
    int* cursor    = (int*)alloc((size_t)N_NODES * 4);
    int* blockSums = (int*)alloc(1024 * 4);
    float* out_scale = (float*)alloc((size_t)N_NODES * 4);
    float* in_scale  = (float*)alloc((size_t)N_NODES * 4);
    int* csr_edge  = (int*)alloc((size_t)N_EDGES * 4);
    u16* h_sum  = (u16*)alloc((size_t)N_NODES * 128 * 2);
    u16* h_prod = (u16*)alloc((size_t)N_NODES * 128 * 2);
    u16* hp     = (u16*)alloc((size_t)N_NODES * 128 * 2);

    (void)in_sizes; (void)n_in; (void)out_size; (void)ws_size;

    int nb = (N_NODES + 1023) / 1024;
    k_zero<<<(N_NODES + 255) / 256, 256, 0, stream>>>(out_deg, in_deg);
    k_deg<<<(N_EDGES + 255) / 256, 256, 0, stream>>>(src, dst, out_deg, in_deg);
    k_scan1<<<nb, 256, 0, stream>>>(in_deg, blockSums);
    k_scan2<<<1, 64, 0, stream>>>(blockSums, nb);
    k_scan3<<<nb, 256, 0, stream>>>(in_deg, out_deg, blockSums, csr_start, cursor, out_scale, in_scale);
    k_scatter<<<(N_EDGES + 255) / 256, 256, 0, stream>>>(src, dst, attr, cursor, csr_edge);
    k_gemm<<<512, 256, 0, stream>>>(feat, w1, w2, out_scale, h_sum, h_prod);
    k_edge<<<(N_NODES + 3) / 4, 256, 0, stream>>>(csr_start, in_deg, csr_edge, h_sum, h_prod, bond, out, hp);
    k_final<<<512, 256, 0, stream>>>(hp, v, in_scale, out);
}